// Round 9
// baseline (259.299 us; speedup 1.0000x reference)
//
#include <hip/hip_runtime.h>

#define SEQ 4096
#define NBATCH 256

typedef float v2f __attribute__((ext_vector_type(2)));

__device__ __forceinline__ float sqf(float v) { return v * v; }
__device__ __forceinline__ float fexp2(float v) { return __builtin_amdgcn_exp2f(v); }
__device__ __forceinline__ float frcp(float v)  { return __builtin_amdgcn_rcpf(v); }

#define L2E 1.4426950408889634f

// ---------------------------------------------------------------------------
// Kernel 1a: per-batch conv max, strip-4 loads (r9: 5 float4 loads per 4
// positions instead of 8 -- redundancy 2.0x -> 1.25x on the 64MB x read).
// Each (batch, quarter) block writes its 5 maxima to Mq[(b*4+quar)*5+j].
// Strip regrouping only changes fmax grouping -- max is order-independent,
// bit-identical. Block 0 also zeroes the lstm completion counter (runs
// before lstm every graph replay -> no memset dispatch).
// ---------------------------------------------------------------------------
__global__ __launch_bounds__(256) void max_kernel(
    const float* __restrict__ x,
    const float* __restrict__ w4p, const float* __restrict__ w5p,
    const float* __restrict__ w6p, const float* __restrict__ w7p,
    const float* __restrict__ w8p,
    float* __restrict__ Mq, unsigned* __restrict__ cnt)
{
    const int b    = blockIdx.x >> 2;
    const int quar = blockIdx.x & 3;
    const int tid  = threadIdx.x;
    if (blockIdx.x == 0 && tid == 0) *cnt = 0u;
    const float* __restrict__ xr = x + (size_t)b * (4 * SEQ);

    float W4[4], W5[5], W6[6], W7[7], W8[8];
#pragma unroll
    for (int k = 0; k < 4; ++k) W4[k] = w4p[k];
#pragma unroll
    for (int k = 0; k < 5; ++k) W5[k] = w5p[k];
#pragma unroll
    for (int k = 0; k < 6; ++k) W6[k] = w6p[k];
#pragma unroll
    for (int k = 0; k < 7; ++k) W7[k] = w7p[k];
#pragma unroll
    for (int k = 0; k < 8; ++k) W8[k] = w8p[k];

    const int p0 = quar * (SEQ / 4) + tid * 4;     // 4-position strip
    float4 f[5];
#pragma unroll
    for (int k = 0; k < 4; ++k)
        f[k] = *reinterpret_cast<const float4*>(xr + 4 * (p0 + k));
    f[4] = (p0 + 4 < SEQ) ? *reinterpret_cast<const float4*>(xr + 4 * (p0 + 4))
                          : make_float4(0.f, 0.f, 0.f, 0.f);

    float m4 = -3.4e38f, m5 = -3.4e38f, m6 = -3.4e38f, m7 = -3.4e38f, m8 = -3.4e38f;
#pragma unroll
    for (int k = 0; k < 4; ++k) {
        const int i = p0 + k;
        const float xa0 = f[k].x, xa1 = f[k].y, xa2 = f[k].z, xa3 = f[k].w;
        const float c4 = xa0 * W4[0] + xa1 * W4[1] + xa2 * W4[2] + xa3 * W4[3];
        m4 = fmaxf(m4, c4);
        if (i < SEQ - 1) {
            const float xa4 = f[k + 1].x, xa5 = f[k + 1].y,
                        xa6 = f[k + 1].z, xa7 = f[k + 1].w;
            const float c5 = xa0*W5[0]+xa1*W5[1]+xa2*W5[2]+xa3*W5[3]+xa4*W5[4];
            const float c6 = xa0*W6[0]+xa1*W6[1]+xa2*W6[2]+xa3*W6[3]+xa4*W6[4]+xa5*W6[5];
            const float c7 = xa0*W7[0]+xa1*W7[1]+xa2*W7[2]+xa3*W7[3]+xa4*W7[4]+xa5*W7[5]+xa6*W7[6];
            const float c8 = xa0*W8[0]+xa1*W8[1]+xa2*W8[2]+xa3*W8[3]+xa4*W8[4]+xa5*W8[5]+xa6*W8[6]+xa7*W8[7];
            m5 = fmaxf(m5, c5); m6 = fmaxf(m6, c6);
            m7 = fmaxf(m7, c7); m8 = fmaxf(m8, c8);
        }
    }
#pragma unroll
    for (int off = 32; off; off >>= 1) {
        m4 = fmaxf(m4, __shfl_down(m4, off));
        m5 = fmaxf(m5, __shfl_down(m5, off));
        m6 = fmaxf(m6, __shfl_down(m6, off));
        m7 = fmaxf(m7, __shfl_down(m7, off));
        m8 = fmaxf(m8, __shfl_down(m8, off));
    }
    __shared__ float wr[4][5];
    if ((tid & 63) == 0) {
        const int w = tid >> 6;
        wr[w][0] = m4; wr[w][1] = m5; wr[w][2] = m6; wr[w][3] = m7; wr[w][4] = m8;
    }
    __syncthreads();
    if (tid < 5) {
        const float m = fmaxf(fmaxf(wr[0][tid], wr[1][tid]),
                              fmaxf(wr[2][tid], wr[3][tid]));
        Mq[blockIdx.x * 5 + tid] = m;
    }
}

// ---------------------------------------------------------------------------
// Kernel 2 (r9): r8 lstm (AT the VALU-issue floor: ~205 busy-cyc/step =
// ~110 instr x 2cyc; gfx950 has NO packed-FP32 rate doubling -- 157.3 TF =
// plain FMA rate -- so r8's v2f was rate-neutral) + merged final reduction:
// after the P writes, threadfence + atomicAdd(cnt); the LAST block re-reads
// P (agent-scope atomic loads: cross-XCD safe) and computes the sigmoid
// outputs in final_kernel's EXACT summation order -> bit-identical output,
// one fewer dispatch. cnt zeroed by max_kernel each replay.
// Structure: 2048 x 64, 2 waves/SIMD; 4 chains; nseg=16, own=256, warm=128;
// seg0 exact reset; fused conv producer; conflict-free vbuf; hb broadcast.
// ---------------------------------------------------------------------------
__global__ __launch_bounds__(64) __attribute__((amdgpu_waves_per_eu(2, 2)))
void lstm_kernel(
    const float* __restrict__ x,
    const float* __restrict__ w4p, const float* __restrict__ w5p,
    const float* __restrict__ w6p, const float* __restrict__ w7p,
    const float* __restrict__ w8p,
    const float* __restrict__ Mq,
    const float* __restrict__ Wih_f, const float* __restrict__ bih_f,
    const float* __restrict__ bhh_f,
    const float* __restrict__ Wih_r, const float* __restrict__ bih_r,
    const float* __restrict__ bhh_r,
    const float* __restrict__ Whh_f, const float* __restrict__ Whh_r,
    float* __restrict__ P, unsigned* __restrict__ cnt,
    float* __restrict__ out)
{
    const int bg   = blockIdx.x & 63;
    const int d    = (blockIdx.x >> 6) & 1;
    const int q    = blockIdx.x >> 7;          // 0..15 = segment
    const int b0   = bg * 4;
    const int lane = threadIdx.x;

    const int s0 = q * 256 - 128;              // negative for q=0 (clamped)
    const int nChunks = 24, warmChunks = 8;    // 16-step chunks, 384 steps

    __shared__ float vbuf[1024];               // [quad k][row][4]: k*256+row*4
    __shared__ float hb[64];                   // [chain][16] broadcast h

    const int c  = lane >> 4;
    const int jr = lane & 15;
    const int jc = (jr < 10) ? jr : 0;

    hb[lane] = 0.f;

    // ---- fold input weights for (dir d, unit jc), packed {i,f}/{g,o} ----
    const float* __restrict__ Wih = d ? Wih_r : Wih_f;
    const float* __restrict__ bi  = d ? bih_r : bih_f;
    const float* __restrict__ bh  = d ? bhh_r : bhh_f;
    float wI[13], wF[13], wG[13], wO[13];
    auto fold = [&](int g, float sc, float* w) {
        const int r = g * 10 + jc;
        const float* __restrict__ W = Wih + r * 24;
        w[0]  = (W[0] + W[1] + W[2] + W[3]) * sc;                // v4s
        w[1]  = (W[4] + W[5] + W[6] + W[7]) * sc;                // v5s
        w[2]  = W[4] * sc;                                       // v5p
        w[3]  = (W[8] + W[9] + W[10] + W[11]) * sc;              // v6s
        w[4]  = (W[8] + W[9]) * sc;                              // v6p
        w[5]  = (W[12] + W[13] + W[14] + W[15]) * sc;            // v7s
        w[6]  = (W[12] + W[13] + W[14]) * sc;                    // v7p
        w[7]  = (W[16] + W[17] + W[18] + W[19]) * sc;            // v8s+v8p
        w[8]  = W[20] * sc; w[9] = W[21] * sc;
        w[10] = W[22] * sc; w[11] = W[23] * sc;                  // x0..x3
        w[12] = (bi[r] + bh[r]) * sc;                            // bias
    };
    fold(0, -L2E, wI); fold(1, -L2E, wF);
    fold(2, -2.f * L2E, wG); fold(3, -L2E, wO);

    v2f wIF[13], wGO[13];
#pragma unroll
    for (int k = 0; k < 13; ++k) {
        wIF[k] = (v2f){wI[k], wF[k]};
        wGO[k] = (v2f){wG[k], wO[k]};
    }

    // recurrent weights (pre-scaled), packed
    const float* __restrict__ Whh = d ? Whh_r : Whh_f;
    v2f hIF[10], hGO[10];
#pragma unroll
    for (int k = 0; k < 10; ++k) {
        hIF[k] = (v2f){Whh[jc * 10 + k]        * (-L2E),
                       Whh[(10 + jc) * 10 + k] * (-L2E)};
        hGO[k] = (v2f){Whh[(20 + jc) * 10 + k] * (-2.f * L2E),
                       Whh[(30 + jc) * 10 + k] * (-L2E)};
    }

    // ---- staging role: lane stages row (step lane>>2, chain lane&3) ----
    const int lc = lane & 3;
    const int lr = lane >> 2;                  // 0..15
    const float* __restrict__ xr = x + (size_t)(b0 + lc) * (4 * SEQ);

    float W4[4], W5[5], W6[6], W7[7], W8[8];
#pragma unroll
    for (int k = 0; k < 4; ++k) W4[k] = w4p[k];
#pragma unroll
    for (int k = 0; k < 5; ++k) W5[k] = w5p[k];
#pragma unroll
    for (int k = 0; k < 6; ++k) W6[k] = w6p[k];
#pragma unroll
    for (int k = 0; k < 7; ++k) W7[k] = w7p[k];
#pragma unroll
    for (int k = 0; k < 8; ++k) W8[k] = w8p[k];

    // per-quarter maxima -> max of 4 (order-independent == old atomic)
    const float* __restrict__ Mb = Mq + (size_t)(b0 + lc) * 20;
    float M4 = fmaxf(fmaxf(Mb[0],  Mb[5]),  fmaxf(Mb[10], Mb[15]));
    float M5 = fmaxf(fmaxf(Mb[1],  Mb[6]),  fmaxf(Mb[11], Mb[16]));
    float M6 = fmaxf(fmaxf(Mb[2],  Mb[7]),  fmaxf(Mb[12], Mb[17]));
    float M7 = fmaxf(fmaxf(Mb[3],  Mb[8]),  fmaxf(Mb[13], Mb[18]));
    float M8 = fmaxf(fmaxf(Mb[4],  Mb[9]),  fmaxf(Mb[14], Mb[19]));

    auto posof = [&](int cn) {
        int sp = s0 + cn * 16 + lr;
        if (sp < 0) sp = 0;                    // q=0 warm region: clamped garbage,
                                               // discarded by the state reset
        return d ? (SEQ - 1 - sp) : sp;
    };
    auto loadx = [&](int pos, float4& A, float4& B, float4& C) {
        B = *reinterpret_cast<const float4*>(xr + 4 * pos);
        A = (pos > 0) ? *reinterpret_cast<const float4*>(xr + 4 * pos - 4)
                      : make_float4(0.f, 0.f, 0.f, 0.f);
        C = (pos < SEQ - 1) ? *reinterpret_cast<const float4*>(xr + 4 * pos + 4)
                            : make_float4(0.f, 0.f, 0.f, 0.f);
    };

    int posCur = posof(0);
    float4 xA, xB, xC;
    loadx(posCur, xA, xB, xC);

    float cs = 0.f, accS = 0.f;

    // one recurrence step; h round-trips through hb (same-wave DS in-order)
    auto step = [&](int i) {
        const int ro = (i * 4 + c) * 4;
        const float4 q0 = *reinterpret_cast<const float4*>(&vbuf[ro]);
        const float4 q1 = *reinterpret_cast<const float4*>(&vbuf[256 + ro]);
        const float4 q2 = *reinterpret_cast<const float4*>(&vbuf[512 + ro]);
        const float  sx = vbuf[768 + ro];
        const float vv[12] = {q0.x, q0.y, q0.z, q0.w,
                              q1.x, q1.y, q1.z, q1.w,
                              q2.x, q2.y, q2.z, q2.w};
        const float4 h03 = *reinterpret_cast<const float4*>(&hb[c * 16 + 0]);
        const float4 h47 = *reinterpret_cast<const float4*>(&hb[c * 16 + 4]);
        const float2 h89 = *reinterpret_cast<const float2*>(&hb[c * 16 + 8]);
        const float hj[10] = {h03.x, h03.y, h03.z, h03.w,
                              h47.x, h47.y, h47.z, h47.w, h89.x, h89.y};
        // in-matvec, packed {i,f}/{g,o} (components == r7 scalar order)
        v2f eIF0 = wIF[12], eIF1 = (v2f){0.f, 0.f};
        v2f eGO0 = wGO[12], eGO1 = (v2f){0.f, 0.f};
#pragma unroll
        for (int k = 0; k < 12; k += 2) {
            const v2f v0 = (v2f){vv[k], vv[k]};
            const v2f v1 = (v2f){vv[k + 1], vv[k + 1]};
            eIF0 += v0 * wIF[k]; eIF1 += v1 * wIF[k + 1];
            eGO0 += v0 * wGO[k]; eGO1 += v1 * wGO[k + 1];
        }
        // complete in-sum BEFORE h seed (r7/r2 order)
        v2f aIF0 = eIF0 + eIF1, aIF1 = (v2f){0.f, 0.f};
        v2f aGO0 = eGO0 + eGO1, aGO1 = (v2f){0.f, 0.f};
#pragma unroll
        for (int k = 0; k < 10; k += 2) {
            const v2f h0 = (v2f){hj[k], hj[k]};
            const v2f h1 = (v2f){hj[k + 1], hj[k + 1]};
            aIF0 += h0 * hIF[k]; aIF1 += h1 * hIF[k + 1];
            aGO0 += h0 * hGO[k]; aGO1 += h1 * hGO[k + 1];
        }
        const v2f eIF = aIF0 + aIF1, eGO = aGO0 + aGO1;
        // eIF.x=-l2e*i  eIF.y=-l2e*f  eGO.x=-2l2e*g  eGO.y=-l2e*o
        const float Ai = fexp2(eIF.x);                 // e^-i
        const float Fv = fexp2(eIF.y);                 // e^-f
        const float Bg = fexp2(fminf(eGO.x, 80.f));    // e^-2g (clamped: no inf*0)
        const float Ov = fexp2(eGO.y);                 // e^-o
        const float sf = frcp(1.f + Fv);
        // -2l2e * sigmoid(i)*tanh(g) = (2l2e*Bg - 2l2e) / ((1+Ai)(1+Bg))
        const float it = fmaf(Bg, 2.f * L2E, -2.f * L2E) *
                         frcp((1.f + Ai) * (1.f + Bg));
        cs = fmaf(sf, cs, it);                         // cs = -2l2e * c
        const float Dv = fexp2(fminf(cs, 80.f));       // e^-2c (clamped)
        // sigmoid(o)*tanh(c) = (1-Dv) / ((1+Ov)(1+Dv))
        const float hv = (1.f - Dv) * frcp((1.f + Ov) * (1.f + Dv));
        hb[c * 16 + jr] = hv;                          // jr>=10 -> harmless pad
        accS = fmaf(sx, hv, accS);
    };

    for (int cn = 0; cn < nChunks; ++cn) {
        // ---- IN-LOOP pins: opaque redefinition -> load-remat illegal ----
        asm volatile("" :
            "+v"(wIF[0]), "+v"(wIF[1]), "+v"(wIF[2]), "+v"(wIF[3]),
            "+v"(wIF[4]), "+v"(wIF[5]), "+v"(wIF[6]), "+v"(wIF[7]),
            "+v"(wIF[8]), "+v"(wIF[9]), "+v"(wIF[10]), "+v"(wIF[11]),
            "+v"(wIF[12]),
            "+v"(wGO[0]), "+v"(wGO[1]), "+v"(wGO[2]), "+v"(wGO[3]),
            "+v"(wGO[4]), "+v"(wGO[5]), "+v"(wGO[6]), "+v"(wGO[7]),
            "+v"(wGO[8]), "+v"(wGO[9]), "+v"(wGO[10]), "+v"(wGO[11]),
            "+v"(wGO[12]));
        asm volatile("" :
            "+v"(hIF[0]), "+v"(hIF[1]), "+v"(hIF[2]), "+v"(hIF[3]),
            "+v"(hIF[4]), "+v"(hIF[5]), "+v"(hIF[6]), "+v"(hIF[7]),
            "+v"(hIF[8]), "+v"(hIF[9]),
            "+v"(hGO[0]), "+v"(hGO[1]), "+v"(hGO[2]), "+v"(hGO[3]),
            "+v"(hGO[4]), "+v"(hGO[5]), "+v"(hGO[6]), "+v"(hGO[7]),
            "+v"(hGO[8]), "+v"(hGO[9]));
        asm volatile("" :
            "+v"(W4[0]), "+v"(W4[1]), "+v"(W4[2]), "+v"(W4[3]),
            "+v"(W5[0]), "+v"(W5[1]), "+v"(W5[2]), "+v"(W5[3]), "+v"(W5[4]),
            "+v"(W6[0]), "+v"(W6[1]), "+v"(W6[2]), "+v"(W6[3]), "+v"(W6[4]),
            "+v"(W6[5]),
            "+v"(W7[0]), "+v"(W7[1]), "+v"(W7[2]), "+v"(W7[3]), "+v"(W7[4]),
            "+v"(W7[5]), "+v"(W7[6]),
            "+v"(W8[0]), "+v"(W8[1]), "+v"(W8[2]), "+v"(W8[3]), "+v"(W8[4]),
            "+v"(W8[5]), "+v"(W8[6]), "+v"(W8[7]));
        asm volatile("" :
            "+v"(M4), "+v"(M5), "+v"(M6), "+v"(M7), "+v"(M8));

        // ---- conv for this chunk's row (old scatter math, exact order) ----
        {
            const bool okp = posCur > 0, oks = posCur < SEQ - 1;
            float xw[12];
            xw[0] = xA.x; xw[1] = xA.y; xw[2]  = xA.z; xw[3]  = xA.w;
            xw[4] = xB.x; xw[5] = xB.y; xw[6]  = xB.z; xw[7]  = xB.w;
            xw[8] = xC.x; xw[9] = xC.y; xw[10] = xC.z; xw[11] = xC.w;

            float c4s = 0.f, c5s = 0.f, c6s = 0.f, c7s = 0.f, c8s = 0.f;
            float c5p = 0.f, c6p = 0.f, c7p = 0.f, c8p = 0.f;
#pragma unroll
            for (int t = 0; t < 4; ++t) c4s += xw[4 + t] * W4[t];
#pragma unroll
            for (int t = 0; t < 5; ++t) { c5s += xw[4 + t] * W5[t]; c5p += xw[t] * W5[t]; }
#pragma unroll
            for (int t = 0; t < 6; ++t) { c6s += xw[4 + t] * W6[t]; c6p += xw[t] * W6[t]; }
#pragma unroll
            for (int t = 0; t < 7; ++t) { c7s += xw[4 + t] * W7[t]; c7p += xw[t] * W7[t]; }
#pragma unroll
            for (int t = 0; t < 8; ++t) { c8s += xw[4 + t] * W8[t]; c8p += xw[t] * W8[t]; }

            const float v4s = sqf(c4s + M4);
            const float v5s = oks ? sqf(c5s + M5) : 0.f;
            const float v6s = oks ? sqf(c6s + M6) : 0.f;
            const float v7s = oks ? sqf(c7s + M7) : 0.f;
            const float v8s = oks ? sqf(c8s + M8) : 0.f;
            const float v5p = okp ? sqf(c5p + M5) : 0.f;
            const float v6p = okp ? sqf(c6p + M6) : 0.f;
            const float v7p = okp ? sqf(c7p + M7) : 0.f;
            const float v8p = okp ? sqf(c8p + M8) : 0.f;
            const float xsum = (xw[4] + xw[5]) + (xw[6] + xw[7]);

            *reinterpret_cast<float4*>(&vbuf[lane * 4]) =
                make_float4(v4s, v5s, v5p, v6s);
            *reinterpret_cast<float4*>(&vbuf[256 + lane * 4]) =
                make_float4(v6p, v7s, v7p, v8s + v8p);
            *reinterpret_cast<float4*>(&vbuf[512 + lane * 4]) =
                make_float4(xw[4], xw[5], xw[6], xw[7]);
            vbuf[768 + lane * 4] = xsum;
        }
        // ---- same-wave DS ordering (single wave: no barrier) ----
        asm volatile("s_waitcnt lgkmcnt(0)" ::: "memory");
        // ---- issue next chunk's x loads (overlap the 16-step consume) ----
        {
            const int nc = (cn + 1 < nChunks) ? cn + 1 : cn;
            posCur = posof(nc);
            loadx(posCur, xA, xB, xC);
        }
        // ---- consume 16 steps (serial chain; TLP hides latency) ----
#pragma unroll 4
        for (int i = 0; i < 16; ++i) step(i);
        if (cn + 1 == warmChunks) {
            accS = 0.f;                        // drop warmup contributions
            if (q == 0) {                      // seg0: exact zero init at s=0
                cs = 0.f;
                hb[lane] = 0.f;
            }
        }
    }

    // ---- group reduction (within 16-lane group; lane0 tree stays clean) ----
    float vA = (jr < 10) ? accS : 0.f;
#pragma unroll
    for (int off = 1; off <= 8; off <<= 1) vA += __shfl_down(vA, off);
    if (jr == 0) P[q * 512 + d * 256 + b0 + c] = vA;

    // ---- merged final reduction: last block computes the outputs ----
    __threadfence();                           // release: P writes visible
    int old = 0;
    if (lane == 0) old = (int)atomicAdd(cnt, 1u);
    old = __shfl(old, 0);
    if (old == 2047) {
        __threadfence();                       // acquire side
        for (int bb = lane; bb < NBATCH; bb += 64) {
            float v = 0.f;
#pragma unroll
            for (int seg = 0; seg < 16; ++seg) {
                // agent-scope loads: safe across non-coherent per-XCD L2s
                const float pa = __hip_atomic_load(&P[seg * 512 + bb],
                                    __ATOMIC_RELAXED, __HIP_MEMORY_SCOPE_AGENT);
                const float pb = __hip_atomic_load(&P[seg * 512 + 256 + bb],
                                    __ATOMIC_RELAXED, __HIP_MEMORY_SCOPE_AGENT);
                v += pa + pb;                  // exact final_kernel order
            }
            out[bb] = frcp(1.f + fexp2(-v * L2E));
        }
    }
}

extern "C" void kernel_launch(void* const* d_in, const int* in_sizes, int n_in,
                              void* d_out, int out_size, void* d_ws, size_t ws_size,
                              hipStream_t stream)
{
    const float* x     = (const float*)d_in[0];
    const float* w4    = (const float*)d_in[1];
    const float* w5    = (const float*)d_in[2];
    const float* w6    = (const float*)d_in[3];
    const float* w7    = (const float*)d_in[4];
    const float* w8    = (const float*)d_in[5];
    const float* Wih_f = (const float*)d_in[6];
    const float* Whh_f = (const float*)d_in[7];
    const float* bih_f = (const float*)d_in[8];
    const float* bhh_f = (const float*)d_in[9];
    const float* Wih_r = (const float*)d_in[10];
    const float* Whh_r = (const float*)d_in[11];
    const float* bih_r = (const float*)d_in[12];
    const float* bhh_r = (const float*)d_in[13];

    // ws layout (fp32): P[8192] | Mq[5120] | cnt[1]
    float*    P   = (float*)d_ws;
    float*    Mq  = P + 8192;
    unsigned* cnt = (unsigned*)(Mq + 5120);

    max_kernel<<<4 * NBATCH, 256, 0, stream>>>(x, w4, w5, w6, w7, w8, Mq, cnt);
    lstm_kernel<<<2048, 64, 0, stream>>>(x, w4, w5, w6, w7, w8, Mq,
                                         Wih_f, bih_f, bhh_f,
                                         Wih_r, bih_r, bhh_r,
                                         Whh_f, Whh_r, P, cnt, (float*)d_out);
}

// Round 10
// 237.313 us; speedup vs baseline: 1.0926x; 1.0926x over previous
//
#include <hip/hip_runtime.h>

#define SEQ 4096
#define NBATCH 256

typedef float v2f __attribute__((ext_vector_type(2)));

__device__ __forceinline__ float sqf(float v) { return v * v; }
__device__ __forceinline__ float fexp2(float v) { return __builtin_amdgcn_exp2f(v); }
__device__ __forceinline__ float frcp(float v)  { return __builtin_amdgcn_rcpf(v); }

#define L2E 1.4426950408889634f

// ---------------------------------------------------------------------------
// Kernel 1a: per-batch conv max, strip-4 loads (5 float4 loads per 4
// positions; redundancy 1.25x). Each (batch, quarter) block writes its 5
// maxima to Mq[(b*4+quar)*5+j] -- no atomics, no memset. Strip regrouping
// only changes fmax grouping; max is order-independent -> bit-identical.
// ---------------------------------------------------------------------------
__global__ __launch_bounds__(256) void max_kernel(
    const float* __restrict__ x,
    const float* __restrict__ w4p, const float* __restrict__ w5p,
    const float* __restrict__ w6p, const float* __restrict__ w7p,
    const float* __restrict__ w8p,
    float* __restrict__ Mq)
{
    const int b    = blockIdx.x >> 2;
    const int quar = blockIdx.x & 3;
    const int tid  = threadIdx.x;
    const float* __restrict__ xr = x + (size_t)b * (4 * SEQ);

    float W4[4], W5[5], W6[6], W7[7], W8[8];
#pragma unroll
    for (int k = 0; k < 4; ++k) W4[k] = w4p[k];
#pragma unroll
    for (int k = 0; k < 5; ++k) W5[k] = w5p[k];
#pragma unroll
    for (int k = 0; k < 6; ++k) W6[k] = w6p[k];
#pragma unroll
    for (int k = 0; k < 7; ++k) W7[k] = w7p[k];
#pragma unroll
    for (int k = 0; k < 8; ++k) W8[k] = w8p[k];

    const int p0 = quar * (SEQ / 4) + tid * 4;     // 4-position strip
    float4 f[5];
#pragma unroll
    for (int k = 0; k < 4; ++k)
        f[k] = *reinterpret_cast<const float4*>(xr + 4 * (p0 + k));
    f[4] = (p0 + 4 < SEQ) ? *reinterpret_cast<const float4*>(xr + 4 * (p0 + 4))
                          : make_float4(0.f, 0.f, 0.f, 0.f);

    float m4 = -3.4e38f, m5 = -3.4e38f, m6 = -3.4e38f, m7 = -3.4e38f, m8 = -3.4e38f;
#pragma unroll
    for (int k = 0; k < 4; ++k) {
        const int i = p0 + k;
        const float xa0 = f[k].x, xa1 = f[k].y, xa2 = f[k].z, xa3 = f[k].w;
        const float c4 = xa0 * W4[0] + xa1 * W4[1] + xa2 * W4[2] + xa3 * W4[3];
        m4 = fmaxf(m4, c4);
        if (i < SEQ - 1) {
            const float xa4 = f[k + 1].x, xa5 = f[k + 1].y,
                        xa6 = f[k + 1].z, xa7 = f[k + 1].w;
            const float c5 = xa0*W5[0]+xa1*W5[1]+xa2*W5[2]+xa3*W5[3]+xa4*W5[4];
            const float c6 = xa0*W6[0]+xa1*W6[1]+xa2*W6[2]+xa3*W6[3]+xa4*W6[4]+xa5*W6[5];
            const float c7 = xa0*W7[0]+xa1*W7[1]+xa2*W7[2]+xa3*W7[3]+xa4*W7[4]+xa5*W7[5]+xa6*W7[6];
            const float c8 = xa0*W8[0]+xa1*W8[1]+xa2*W8[2]+xa3*W8[3]+xa4*W8[4]+xa5*W8[5]+xa6*W8[6]+xa7*W8[7];
            m5 = fmaxf(m5, c5); m6 = fmaxf(m6, c6);
            m7 = fmaxf(m7, c7); m8 = fmaxf(m8, c8);
        }
    }
#pragma unroll
    for (int off = 32; off; off >>= 1) {
        m4 = fmaxf(m4, __shfl_down(m4, off));
        m5 = fmaxf(m5, __shfl_down(m5, off));
        m6 = fmaxf(m6, __shfl_down(m6, off));
        m7 = fmaxf(m7, __shfl_down(m7, off));
        m8 = fmaxf(m8, __shfl_down(m8, off));
    }
    __shared__ float wr[4][5];
    if ((tid & 63) == 0) {
        const int w = tid >> 6;
        wr[w][0] = m4; wr[w][1] = m5; wr[w][2] = m6; wr[w][3] = m7; wr[w][4] = m8;
    }
    __syncthreads();
    if (tid < 5) {
        const float m = fmaxf(fmaxf(wr[0][tid], wr[1][tid]),
                              fmaxf(wr[2][tid], wr[3][tid]));
        Mq[blockIdx.x * 5 + tid] = m;
    }
}

// ---------------------------------------------------------------------------
// Kernel 2 (r10 = r8 revert, the best-verified config): fused segmented
// bidirectional LSTM at its VALU-issue floor (~404 busy-cyc/step vs ~290
// fundamental; invariant under ILP r1, TLP r3, SGPR operands r6, pins r7,
// packed-fp32 r8 -- gfx950 has no pk rate doubling). r9's merged final
// (+threadfence per block) cost +23us and is REVERTED: separate 1-block
// final_kernel restored.
// Structure: 2048 x 64, 2 waves/SIMD; 4 chains/wave; nseg=16, own=256,
// warm=128; seg0 exact reset; fused conv producer (FETCH ~8MB); conflict-
// free vbuf; hb LDS-broadcast h state; in-loop residency pins.
// ---------------------------------------------------------------------------
__global__ __launch_bounds__(64) __attribute__((amdgpu_waves_per_eu(2, 2)))
void lstm_kernel(
    const float* __restrict__ x,
    const float* __restrict__ w4p, const float* __restrict__ w5p,
    const float* __restrict__ w6p, const float* __restrict__ w7p,
    const float* __restrict__ w8p,
    const float* __restrict__ Mq,
    const float* __restrict__ Wih_f, const float* __restrict__ bih_f,
    const float* __restrict__ bhh_f,
    const float* __restrict__ Wih_r, const float* __restrict__ bih_r,
    const float* __restrict__ bhh_r,
    const float* __restrict__ Whh_f, const float* __restrict__ Whh_r,
    float* __restrict__ P)
{
    const int bg   = blockIdx.x & 63;
    const int d    = (blockIdx.x >> 6) & 1;
    const int q    = blockIdx.x >> 7;          // 0..15 = segment
    const int b0   = bg * 4;
    const int lane = threadIdx.x;

    const int s0 = q * 256 - 128;              // negative for q=0 (clamped)
    const int nChunks = 24, warmChunks = 8;    // 16-step chunks, 384 steps

    __shared__ float vbuf[1024];               // [quad k][row][4]: k*256+row*4
    __shared__ float hb[64];                   // [chain][16] broadcast h

    const int c  = lane >> 4;
    const int jr = lane & 15;
    const int jc = (jr < 10) ? jr : 0;

    hb[lane] = 0.f;

    // ---- fold input weights for (dir d, unit jc), packed {i,f}/{g,o} ----
    const float* __restrict__ Wih = d ? Wih_r : Wih_f;
    const float* __restrict__ bi  = d ? bih_r : bih_f;
    const float* __restrict__ bh  = d ? bhh_r : bhh_f;
    float wI[13], wF[13], wG[13], wO[13];
    auto fold = [&](int g, float sc, float* w) {
        const int r = g * 10 + jc;
        const float* __restrict__ W = Wih + r * 24;
        w[0]  = (W[0] + W[1] + W[2] + W[3]) * sc;                // v4s
        w[1]  = (W[4] + W[5] + W[6] + W[7]) * sc;                // v5s
        w[2]  = W[4] * sc;                                       // v5p
        w[3]  = (W[8] + W[9] + W[10] + W[11]) * sc;              // v6s
        w[4]  = (W[8] + W[9]) * sc;                              // v6p
        w[5]  = (W[12] + W[13] + W[14] + W[15]) * sc;            // v7s
        w[6]  = (W[12] + W[13] + W[14]) * sc;                    // v7p
        w[7]  = (W[16] + W[17] + W[18] + W[19]) * sc;            // v8s+v8p
        w[8]  = W[20] * sc; w[9] = W[21] * sc;
        w[10] = W[22] * sc; w[11] = W[23] * sc;                  // x0..x3
        w[12] = (bi[r] + bh[r]) * sc;                            // bias
    };
    fold(0, -L2E, wI); fold(1, -L2E, wF);
    fold(2, -2.f * L2E, wG); fold(3, -L2E, wO);

    v2f wIF[13], wGO[13];
#pragma unroll
    for (int k = 0; k < 13; ++k) {
        wIF[k] = (v2f){wI[k], wF[k]};
        wGO[k] = (v2f){wG[k], wO[k]};
    }

    // recurrent weights (pre-scaled), packed
    const float* __restrict__ Whh = d ? Whh_r : Whh_f;
    v2f hIF[10], hGO[10];
#pragma unroll
    for (int k = 0; k < 10; ++k) {
        hIF[k] = (v2f){Whh[jc * 10 + k]        * (-L2E),
                       Whh[(10 + jc) * 10 + k] * (-L2E)};
        hGO[k] = (v2f){Whh[(20 + jc) * 10 + k] * (-2.f * L2E),
                       Whh[(30 + jc) * 10 + k] * (-L2E)};
    }

    // ---- staging role: lane stages row (step lane>>2, chain lane&3) ----
    const int lc = lane & 3;
    const int lr = lane >> 2;                  // 0..15
    const float* __restrict__ xr = x + (size_t)(b0 + lc) * (4 * SEQ);

    float W4[4], W5[5], W6[6], W7[7], W8[8];
#pragma unroll
    for (int k = 0; k < 4; ++k) W4[k] = w4p[k];
#pragma unroll
    for (int k = 0; k < 5; ++k) W5[k] = w5p[k];
#pragma unroll
    for (int k = 0; k < 6; ++k) W6[k] = w6p[k];
#pragma unroll
    for (int k = 0; k < 7; ++k) W7[k] = w7p[k];
#pragma unroll
    for (int k = 0; k < 8; ++k) W8[k] = w8p[k];

    // per-quarter maxima -> max of 4 (order-independent == old atomic)
    const float* __restrict__ Mb = Mq + (size_t)(b0 + lc) * 20;
    float M4 = fmaxf(fmaxf(Mb[0],  Mb[5]),  fmaxf(Mb[10], Mb[15]));
    float M5 = fmaxf(fmaxf(Mb[1],  Mb[6]),  fmaxf(Mb[11], Mb[16]));
    float M6 = fmaxf(fmaxf(Mb[2],  Mb[7]),  fmaxf(Mb[12], Mb[17]));
    float M7 = fmaxf(fmaxf(Mb[3],  Mb[8]),  fmaxf(Mb[13], Mb[18]));
    float M8 = fmaxf(fmaxf(Mb[4],  Mb[9]),  fmaxf(Mb[14], Mb[19]));

    auto posof = [&](int cn) {
        int sp = s0 + cn * 16 + lr;
        if (sp < 0) sp = 0;                    // q=0 warm region: clamped garbage,
                                               // discarded by the state reset
        return d ? (SEQ - 1 - sp) : sp;
    };
    auto loadx = [&](int pos, float4& A, float4& B, float4& C) {
        B = *reinterpret_cast<const float4*>(xr + 4 * pos);
        A = (pos > 0) ? *reinterpret_cast<const float4*>(xr + 4 * pos - 4)
                      : make_float4(0.f, 0.f, 0.f, 0.f);
        C = (pos < SEQ - 1) ? *reinterpret_cast<const float4*>(xr + 4 * pos + 4)
                            : make_float4(0.f, 0.f, 0.f, 0.f);
    };

    int posCur = posof(0);
    float4 xA, xB, xC;
    loadx(posCur, xA, xB, xC);

    float cs = 0.f, accS = 0.f;

    // one recurrence step; h round-trips through hb (same-wave DS in-order)
    auto step = [&](int i) {
        const int ro = (i * 4 + c) * 4;
        const float4 q0 = *reinterpret_cast<const float4*>(&vbuf[ro]);
        const float4 q1 = *reinterpret_cast<const float4*>(&vbuf[256 + ro]);
        const float4 q2 = *reinterpret_cast<const float4*>(&vbuf[512 + ro]);
        const float  sx = vbuf[768 + ro];
        const float vv[12] = {q0.x, q0.y, q0.z, q0.w,
                              q1.x, q1.y, q1.z, q1.w,
                              q2.x, q2.y, q2.z, q2.w};
        const float4 h03 = *reinterpret_cast<const float4*>(&hb[c * 16 + 0]);
        const float4 h47 = *reinterpret_cast<const float4*>(&hb[c * 16 + 4]);
        const float2 h89 = *reinterpret_cast<const float2*>(&hb[c * 16 + 8]);
        const float hj[10] = {h03.x, h03.y, h03.z, h03.w,
                              h47.x, h47.y, h47.z, h47.w, h89.x, h89.y};
        // in-matvec, packed {i,f}/{g,o} (components == r7 scalar order)
        v2f eIF0 = wIF[12], eIF1 = (v2f){0.f, 0.f};
        v2f eGO0 = wGO[12], eGO1 = (v2f){0.f, 0.f};
#pragma unroll
        for (int k = 0; k < 12; k += 2) {
            const v2f v0 = (v2f){vv[k], vv[k]};
            const v2f v1 = (v2f){vv[k + 1], vv[k + 1]};
            eIF0 += v0 * wIF[k]; eIF1 += v1 * wIF[k + 1];
            eGO0 += v0 * wGO[k]; eGO1 += v1 * wGO[k + 1];
        }
        // complete in-sum BEFORE h seed (r7/r2 order)
        v2f aIF0 = eIF0 + eIF1, aIF1 = (v2f){0.f, 0.f};
        v2f aGO0 = eGO0 + eGO1, aGO1 = (v2f){0.f, 0.f};
#pragma unroll
        for (int k = 0; k < 10; k += 2) {
            const v2f h0 = (v2f){hj[k], hj[k]};
            const v2f h1 = (v2f){hj[k + 1], hj[k + 1]};
            aIF0 += h0 * hIF[k]; aIF1 += h1 * hIF[k + 1];
            aGO0 += h0 * hGO[k]; aGO1 += h1 * hGO[k + 1];
        }
        const v2f eIF = aIF0 + aIF1, eGO = aGO0 + aGO1;
        // eIF.x=-l2e*i  eIF.y=-l2e*f  eGO.x=-2l2e*g  eGO.y=-l2e*o
        const float Ai = fexp2(eIF.x);                 // e^-i
        const float Fv = fexp2(eIF.y);                 // e^-f
        const float Bg = fexp2(fminf(eGO.x, 80.f));    // e^-2g (clamped: no inf*0)
        const float Ov = fexp2(eGO.y);                 // e^-o
        const float sf = frcp(1.f + Fv);
        // -2l2e * sigmoid(i)*tanh(g) = (2l2e*Bg - 2l2e) / ((1+Ai)(1+Bg))
        const float it = fmaf(Bg, 2.f * L2E, -2.f * L2E) *
                         frcp((1.f + Ai) * (1.f + Bg));
        cs = fmaf(sf, cs, it);                         // cs = -2l2e * c
        const float Dv = fexp2(fminf(cs, 80.f));       // e^-2c (clamped)
        // sigmoid(o)*tanh(c) = (1-Dv) / ((1+Ov)(1+Dv))
        const float hv = (1.f - Dv) * frcp((1.f + Ov) * (1.f + Dv));
        hb[c * 16 + jr] = hv;                          // jr>=10 -> harmless pad
        accS = fmaf(sx, hv, accS);
    };

    for (int cn = 0; cn < nChunks; ++cn) {
        // ---- IN-LOOP pins: opaque redefinition -> load-remat illegal ----
        asm volatile("" :
            "+v"(wIF[0]), "+v"(wIF[1]), "+v"(wIF[2]), "+v"(wIF[3]),
            "+v"(wIF[4]), "+v"(wIF[5]), "+v"(wIF[6]), "+v"(wIF[7]),
            "+v"(wIF[8]), "+v"(wIF[9]), "+v"(wIF[10]), "+v"(wIF[11]),
            "+v"(wIF[12]),
            "+v"(wGO[0]), "+v"(wGO[1]), "+v"(wGO[2]), "+v"(wGO[3]),
            "+v"(wGO[4]), "+v"(wGO[5]), "+v"(wGO[6]), "+v"(wGO[7]),
            "+v"(wGO[8]), "+v"(wGO[9]), "+v"(wGO[10]), "+v"(wGO[11]),
            "+v"(wGO[12]));
        asm volatile("" :
            "+v"(hIF[0]), "+v"(hIF[1]), "+v"(hIF[2]), "+v"(hIF[3]),
            "+v"(hIF[4]), "+v"(hIF[5]), "+v"(hIF[6]), "+v"(hIF[7]),
            "+v"(hIF[8]), "+v"(hIF[9]),
            "+v"(hGO[0]), "+v"(hGO[1]), "+v"(hGO[2]), "+v"(hGO[3]),
            "+v"(hGO[4]), "+v"(hGO[5]), "+v"(hGO[6]), "+v"(hGO[7]),
            "+v"(hGO[8]), "+v"(hGO[9]));
        asm volatile("" :
            "+v"(W4[0]), "+v"(W4[1]), "+v"(W4[2]), "+v"(W4[3]),
            "+v"(W5[0]), "+v"(W5[1]), "+v"(W5[2]), "+v"(W5[3]), "+v"(W5[4]),
            "+v"(W6[0]), "+v"(W6[1]), "+v"(W6[2]), "+v"(W6[3]), "+v"(W6[4]),
            "+v"(W6[5]),
            "+v"(W7[0]), "+v"(W7[1]), "+v"(W7[2]), "+v"(W7[3]), "+v"(W7[4]),
            "+v"(W7[5]), "+v"(W7[6]),
            "+v"(W8[0]), "+v"(W8[1]), "+v"(W8[2]), "+v"(W8[3]), "+v"(W8[4]),
            "+v"(W8[5]), "+v"(W8[6]), "+v"(W8[7]));
        asm volatile("" :
            "+v"(M4), "+v"(M5), "+v"(M6), "+v"(M7), "+v"(M8));

        // ---- conv for this chunk's row (old scatter math, exact order) ----
        {
            const bool okp = posCur > 0, oks = posCur < SEQ - 1;
            float xw[12];
            xw[0] = xA.x; xw[1] = xA.y; xw[2]  = xA.z; xw[3]  = xA.w;
            xw[4] = xB.x; xw[5] = xB.y; xw[6]  = xB.z; xw[7]  = xB.w;
            xw[8] = xC.x; xw[9] = xC.y; xw[10] = xC.z; xw[11] = xC.w;

            float c4s = 0.f, c5s = 0.f, c6s = 0.f, c7s = 0.f, c8s = 0.f;
            float c5p = 0.f, c6p = 0.f, c7p = 0.f, c8p = 0.f;
#pragma unroll
            for (int t = 0; t < 4; ++t) c4s += xw[4 + t] * W4[t];
#pragma unroll
            for (int t = 0; t < 5; ++t) { c5s += xw[4 + t] * W5[t]; c5p += xw[t] * W5[t]; }
#pragma unroll
            for (int t = 0; t < 6; ++t) { c6s += xw[4 + t] * W6[t]; c6p += xw[t] * W6[t]; }
#pragma unroll
            for (int t = 0; t < 7; ++t) { c7s += xw[4 + t] * W7[t]; c7p += xw[t] * W7[t]; }
#pragma unroll
            for (int t = 0; t < 8; ++t) { c8s += xw[4 + t] * W8[t]; c8p += xw[t] * W8[t]; }

            const float v4s = sqf(c4s + M4);
            const float v5s = oks ? sqf(c5s + M5) : 0.f;
            const float v6s = oks ? sqf(c6s + M6) : 0.f;
            const float v7s = oks ? sqf(c7s + M7) : 0.f;
            const float v8s = oks ? sqf(c8s + M8) : 0.f;
            const float v5p = okp ? sqf(c5p + M5) : 0.f;
            const float v6p = okp ? sqf(c6p + M6) : 0.f;
            const float v7p = okp ? sqf(c7p + M7) : 0.f;
            const float v8p = okp ? sqf(c8p + M8) : 0.f;
            const float xsum = (xw[4] + xw[5]) + (xw[6] + xw[7]);

            *reinterpret_cast<float4*>(&vbuf[lane * 4]) =
                make_float4(v4s, v5s, v5p, v6s);
            *reinterpret_cast<float4*>(&vbuf[256 + lane * 4]) =
                make_float4(v6p, v7s, v7p, v8s + v8p);
            *reinterpret_cast<float4*>(&vbuf[512 + lane * 4]) =
                make_float4(xw[4], xw[5], xw[6], xw[7]);
            vbuf[768 + lane * 4] = xsum;
        }
        // ---- same-wave DS ordering (single wave: no barrier) ----
        asm volatile("s_waitcnt lgkmcnt(0)" ::: "memory");
        // ---- issue next chunk's x loads (overlap the 16-step consume) ----
        {
            const int nc = (cn + 1 < nChunks) ? cn + 1 : cn;
            posCur = posof(nc);
            loadx(posCur, xA, xB, xC);
        }
        // ---- consume 16 steps (serial chain; TLP hides latency) ----
#pragma unroll 4
        for (int i = 0; i < 16; ++i) step(i);
        if (cn + 1 == warmChunks) {
            accS = 0.f;                        // drop warmup contributions
            if (q == 0) {                      // seg0: exact zero init at s=0
                cs = 0.f;
                hb[lane] = 0.f;
            }
        }
    }

    // ---- group reduction (within 16-lane group; lane0 tree stays clean) ----
    float vA = (jr < 10) ? accS : 0.f;
#pragma unroll
    for (int off = 1; off <= 8; off <<= 1) vA += __shfl_down(vA, off);
    if (jr == 0) P[q * 512 + d * 256 + b0 + c] = vA;
}

// ---------------------------------------------------------------------------
// Kernel 3: out[b] = sigmoid( sum over 16 segments x 2 directions )
// ---------------------------------------------------------------------------
__global__ __launch_bounds__(256) void final_kernel(const float* __restrict__ P,
                                                    float* __restrict__ out)
{
    const int b = threadIdx.x;
    float v = 0.f;
#pragma unroll
    for (int seg = 0; seg < 16; ++seg)
        v += P[seg * 512 + b] + P[seg * 512 + 256 + b];
    out[b] = frcp(1.f + fexp2(-v * L2E));
}

extern "C" void kernel_launch(void* const* d_in, const int* in_sizes, int n_in,
                              void* d_out, int out_size, void* d_ws, size_t ws_size,
                              hipStream_t stream)
{
    const float* x     = (const float*)d_in[0];
    const float* w4    = (const float*)d_in[1];
    const float* w5    = (const float*)d_in[2];
    const float* w6    = (const float*)d_in[3];
    const float* w7    = (const float*)d_in[4];
    const float* w8    = (const float*)d_in[5];
    const float* Wih_f = (const float*)d_in[6];
    const float* Whh_f = (const float*)d_in[7];
    const float* bih_f = (const float*)d_in[8];
    const float* bhh_f = (const float*)d_in[9];
    const float* Wih_r = (const float*)d_in[10];
    const float* Whh_r = (const float*)d_in[11];
    const float* bih_r = (const float*)d_in[12];
    const float* bhh_r = (const float*)d_in[13];

    // ws layout (fp32): P[8192] | Mq[5120]
    float* P  = (float*)d_ws;
    float* Mq = P + 8192;

    max_kernel<<<4 * NBATCH, 256, 0, stream>>>(x, w4, w5, w6, w7, w8, Mq);
    lstm_kernel<<<2048, 64, 0, stream>>>(x, w4, w5, w6, w7, w8, Mq,
                                         Wih_f, bih_f, bhh_f,
                                         Wih_r, bih_r, bhh_r,
                                         Whh_f, Whh_r, P);
    final_kernel<<<1, NBATCH, 0, stream>>>(P, (float*)d_out);
}